// Round 1
// baseline (133.413 us; speedup 1.0000x reference)
//
#include <hip/hip_runtime.h>
#include <math.h>

#define BB 2
#define C_IN 32
#define HH 64
#define WW 64
#define J (HH*WW)        // 4096
#define HID 64
#define C_OUT 32
#define S 256
#define JT 16            // j's per block
#define JPT 4            // j's per thread (4 waves * 4 = 16)
#define SH 128           // s-half staged in LDS at a time

__device__ __forceinline__ float gelu_exact(float x) {
    return 0.5f * x * (1.0f + erff(x * 0.70710678118654752f));
}

// u[b,s,hid] = b1[hid] - sx*W1[0,hid] - sy*W1[1,hid] + sum_c vp[b,idx,c]*W1[2+c,hid]
__global__ __launch_bounds__(64) void nystrom_prep(const float* __restrict__ v,
    const int* __restrict__ indices, const float* __restrict__ W1,
    const float* __restrict__ b1, float* __restrict__ u)
{
    int bs  = blockIdx.x;            // 0..B*S-1
    int b   = bs / S;
    int s   = bs % S;
    int hid = threadIdx.x;           // 0..63
    int idx = indices[s];
    float sx = (float)(idx & (WW - 1)) * (1.0f / (WW - 1));
    float sy = (float)(idx >> 6)       * (1.0f / (HH - 1));
    float acc = b1[hid] - sx * W1[hid] - sy * W1[HID + hid];
    const float* vb = v + (size_t)b * C_IN * J + idx;
    #pragma unroll
    for (int c = 0; c < C_IN; ++c) {
        acc += vb[c * J] * W1[(2 + c) * HID + hid];
    }
    u[((size_t)b * S + s) * HID + hid] = acc;
}

__global__ __launch_bounds__(256) void nystrom_main(const float* __restrict__ u,
    const float* __restrict__ W1, const float* __restrict__ W2,
    const float* __restrict__ b2, float* __restrict__ out)
{
    __shared__ float lds[SH * HID];  // 32 KB; reused for G in epilogue
    int tid = threadIdx.x;
    int blk = blockIdx.x;            // 0..B*(J/JT)-1
    int b   = blk / (J / JT);
    int j0  = (blk % (J / JT)) * JT;
    int hid = tid & 63;
    int g   = tid >> 6;              // wave id 0..3

    float w1x = W1[hid];
    float w1y = W1[HID + hid];
    float cj[JPT], acc[JPT];
    #pragma unroll
    for (int t = 0; t < JPT; ++t) {
        int j = j0 + g * JPT + t;
        float xj = (float)(j & (WW - 1)) * (1.0f / (WW - 1));
        float yj = (float)(j >> 6)       * (1.0f / (HH - 1));
        cj[t]  = xj * w1x + yj * w1y;
        acc[t] = 0.0f;
    }

    const float* ub = u + (size_t)b * S * HID;
    for (int half = 0; half < 2; ++half) {
        __syncthreads();  // protect lds reuse across halves
        const float4* src = (const float4*)(ub + half * SH * HID);
        float4* dst = (float4*)lds;
        #pragma unroll
        for (int i = 0; i < 8; ++i) {           // 8 * 256 * 4 floats = 8192
            dst[i * 256 + tid] = src[i * 256 + tid];
        }
        __syncthreads();
        #pragma unroll 4
        for (int s = 0; s < SH; ++s) {
            float uv = lds[s * HID + hid];      // 64 lanes, stride-1 -> conflict-free
            #pragma unroll
            for (int t = 0; t < JPT; ++t) {
                acc[t] += gelu_exact(cj[t] + uv);
            }
        }
    }

    __syncthreads();
    // G[jt][hid] with padded stride 65 (conflict-free epilogue reads)
    #pragma unroll
    for (int t = 0; t < JPT; ++t) {
        lds[(g * JPT + t) * 65 + hid] = acc[t];
    }
    __syncthreads();

    // epilogue: out[b,co,j0+jt] = (1/S) * sum_hid G[jt][hid]*W2[hid,co] + b2[co]
    #pragma unroll
    for (int iter = 0; iter < 2; ++iter) {
        int jt = tid & 15;
        int co = (tid >> 4) + iter * 16;
        float sum = 0.0f;
        #pragma unroll
        for (int h = 0; h < HID; ++h) {
            sum += lds[jt * 65 + h] * W2[h * C_OUT + co];
        }
        out[(size_t)b * C_OUT * J + (size_t)co * J + j0 + jt] = sum * (1.0f / S) + b2[co];
    }
}

extern "C" void kernel_launch(void* const* d_in, const int* in_sizes, int n_in,
                              void* d_out, int out_size, void* d_ws, size_t ws_size,
                              hipStream_t stream) {
    const float* v       = (const float*)d_in[0];
    const int*   indices = (const int*)  d_in[1];
    const float* W1      = (const float*)d_in[2];
    const float* b1      = (const float*)d_in[3];
    const float* W2      = (const float*)d_in[4];
    const float* b2      = (const float*)d_in[5];
    float* out = (float*)d_out;
    float* u   = (float*)d_ws;   // B*S*HID*4 = 128 KB

    hipLaunchKernelGGL(nystrom_prep, dim3(BB * S), dim3(64), 0, stream,
                       v, indices, W1, b1, u);
    hipLaunchKernelGGL(nystrom_main, dim3(BB * (J / JT)), dim3(256), 0, stream,
                       u, W1, W2, b2, out);
}

// Round 2
// 49.442 us; speedup vs baseline: 2.6984x; 2.6984x over previous
//
#include <hip/hip_runtime.h>
#include <math.h>

#define BB 2
#define C_IN 32
#define HH 64
#define WW 64
#define J (HH*WW)        // 4096
#define HID 64
#define C_OUT 32
#define S 256
#define JT 8             // j's per block
#define JPT 2            // j's per thread (4 waves * 2 = 8)
#define SH 128           // s-half staged in LDS at a time

// tanh-approx gelu, branch-free:
// gelu(x) ~= x - x / (1 + exp2(A*x + B*x^3))
// A = 2*sqrt(2/pi)*log2(e), B = A*0.044715
#define GELU_A 2.3022043f
#define GELU_B 0.10294306f

// u[b,s,hid] = b1[hid] - sx*W1[0,hid] - sy*W1[1,hid] + sum_c vp[b,idx,c]*W1[2+c,hid]
__global__ __launch_bounds__(64) void nystrom_prep(const float* __restrict__ v,
    const int* __restrict__ indices, const float* __restrict__ W1,
    const float* __restrict__ b1, float* __restrict__ u)
{
    int bs  = blockIdx.x;            // 0..B*S-1
    int b   = bs / S;
    int s   = bs % S;
    int hid = threadIdx.x;           // 0..63
    int idx = indices[s];
    float sx = (float)(idx & (WW - 1)) * (1.0f / (WW - 1));
    float sy = (float)(idx >> 6)       * (1.0f / (HH - 1));
    float acc = b1[hid] - sx * W1[hid] - sy * W1[HID + hid];
    const float* vb = v + (size_t)b * C_IN * J + idx;
    #pragma unroll
    for (int c = 0; c < C_IN; ++c) {
        acc += vb[c * J] * W1[(2 + c) * HID + hid];
    }
    u[((size_t)b * S + s) * HID + hid] = acc;
}

__global__ __launch_bounds__(256) void nystrom_main(const float* __restrict__ u,
    const float* __restrict__ W1, const float* __restrict__ W2,
    const float* __restrict__ b2, float* __restrict__ out)
{
    __shared__ float lds[SH * HID];  // 32 KB; reused for G in epilogue
    int tid = threadIdx.x;
    int blk = blockIdx.x;            // 0..B*(J/JT)-1
    int b   = blk / (J / JT);
    int j0  = (blk % (J / JT)) * JT;
    int hid = tid & 63;
    int g   = tid >> 6;              // wave id 0..3

    float w1x = W1[hid];
    float w1y = W1[HID + hid];
    float cj[JPT], acc[JPT];
    #pragma unroll
    for (int t = 0; t < JPT; ++t) {
        int j = j0 + g * JPT + t;
        float xj = (float)(j & (WW - 1)) * (1.0f / (WW - 1));
        float yj = (float)(j >> 6)       * (1.0f / (HH - 1));
        cj[t]  = xj * w1x + yj * w1y;
        acc[t] = 0.0f;
    }

    const float* ub = u + (size_t)b * S * HID;
    for (int half = 0; half < 2; ++half) {
        __syncthreads();  // protect lds reuse across halves
        const float4* src = (const float4*)(ub + half * SH * HID);
        float4* dst = (float4*)lds;
        #pragma unroll
        for (int i = 0; i < 8; ++i) {           // 8 * 256 * 4 floats = 8192
            dst[i * 256 + tid] = src[i * 256 + tid];
        }
        __syncthreads();
        #pragma unroll 4
        for (int s = 0; s < SH; ++s) {
            float uv = lds[s * HID + hid];      // 64 lanes, stride-1 -> conflict-free
            #pragma unroll
            for (int t = 0; t < JPT; ++t) {
                float x  = cj[t] + uv;
                float x2 = x * x;
                float p  = __builtin_fmaf(GELU_B, x2, GELU_A);
                float e  = __builtin_amdgcn_exp2f(p * x);
                float r  = __builtin_amdgcn_rcpf(e + 1.0f);
                acc[t]   = __builtin_fmaf(-x, r, acc[t] + x);
            }
        }
    }

    __syncthreads();
    // G[jt][hid] with padded stride 65 (conflict-free epilogue reads)
    #pragma unroll
    for (int t = 0; t < JPT; ++t) {
        lds[(g * JPT + t) * 65 + hid] = acc[t];
    }
    __syncthreads();

    // epilogue: out[b,co,j0+jt] = (1/S) * sum_hid G[jt][hid]*W2[hid,co] + b2[co]
    {
        int jt = tid & (JT - 1);
        int co = tid >> 3;           // 256 threads = 8 j * 32 co
        float sum = 0.0f;
        #pragma unroll
        for (int h = 0; h < HID; ++h) {
            sum += lds[jt * 65 + h] * W2[h * C_OUT + co];
        }
        out[(size_t)b * C_OUT * J + (size_t)co * J + j0 + jt] = sum * (1.0f / S) + b2[co];
    }
}

extern "C" void kernel_launch(void* const* d_in, const int* in_sizes, int n_in,
                              void* d_out, int out_size, void* d_ws, size_t ws_size,
                              hipStream_t stream) {
    const float* v       = (const float*)d_in[0];
    const int*   indices = (const int*)  d_in[1];
    const float* W1      = (const float*)d_in[2];
    const float* b1      = (const float*)d_in[3];
    const float* W2      = (const float*)d_in[4];
    const float* b2      = (const float*)d_in[5];
    float* out = (float*)d_out;
    float* u   = (float*)d_ws;   // B*S*HID*4 = 128 KB

    hipLaunchKernelGGL(nystrom_prep, dim3(BB * S), dim3(64), 0, stream,
                       v, indices, W1, b1, u);
    hipLaunchKernelGGL(nystrom_main, dim3(BB * (J / JT)), dim3(256), 0, stream,
                       u, W1, W2, b2, out);
}